// Round 18
// baseline (42.299 us; speedup 1.0000x reference)
//
#include <hip/hip_runtime.h>

// MSCA fused multi-scale depthwise conv chain, one workgroup per (b,c) plane.
// x:[8,256,64,64] f32 -> (attn_0, attn_1, attn_2) each [8,256,64,64] f32.
//
// R17 = R14 skeleton at 4 px/thread, 1024-thread blocks: live set ~55-60
// floats fits a 64-VGPR cap NATURALLY -> 2 blocks/CU x 16 waves = 32 waves/CU
// (R7/R8/R12 spilled because caps were forced below the ~110-float live set
// of the 8px version; this shrinks the live set instead).
//  P1: 5x5, x direct from global (guarded rows, L2-hot); scatter ATT_T.  B1
//  P2: T-strip read; a0y -> Y0; a1y -> Y1; a2y -> Y2 (packed chain).     B2
//  P3: staggered Y reads + a0x/a1x/a2x + products + stores.
// Strips of 4 in 16-lane DPP rows (each row = one maj exactly); halos via
// row_shr/shl 1,2,3 hoisted-then-selected (R6 lesson).
// Transpose involution swizzle (verified):
//   scatter:  buf[(4*l16+e)*68 + (maj ^ (l16<<2))]     (2-way conflicts, free)
//   strip rd: buf[maj*68 + ((l16 ^ ((maj>>2)&15))<<2) + e]   (1x b128)
// LDS: RT, R0, R1, R2 = 4 x 4352 w = 69632 B. launch_bounds(1024,8): cap 64.

#define RW 4352                    // 64*68 per region
#define LDS_WORDS (4 * RW)         // 17408 words = 69632 B

typedef float v2f __attribute__((ext_vector_type(2)));

template<int C>
__device__ __forceinline__ float dpp(float v) {
    return __int_as_float(__builtin_amdgcn_update_dpp(
        0, __float_as_int(v), C, 0xF, 0xF, false));
}
// row_shr:1/2/3 = 0x111/0x112/0x113 ; row_shl:1/2/3 = 0x101/0x102/0x103

__device__ __forceinline__ void ld4p(const float* p, v2f* w) {
    float4 q = *(const float4*)p;
    w[0].x = q.x; w[0].y = q.y; w[1].x = q.z; w[1].y = q.w;
}
__device__ __forceinline__ void st4p(float* p, v2f a, v2f b) {
    float4 q; q.x = a.x; q.y = a.y; q.z = b.x; q.w = b.y;
    *(float4*)p = q;
}
__device__ __forceinline__ float elem(const v2f* a, int e) {
    return (e & 1) ? a[e >> 1].y : a[e >> 1].x;
}

// Packed conv (R3/R13-proven core): window f[i] = wnd[i/2].{x,y};
// out j=2k+{0,1}, k<NP: A[k] += wt[v] * f[j + v + TAPOFF].
template<int K, int TAPOFF, int NP>
__device__ __forceinline__ void conv_acc(const float* __restrict__ wrow,
                                         const v2f* wnd, v2f* A) {
    #pragma unroll
    for (int v = 0; v < K; v++) {
        const float w = wrow[v];
        const int u = v + TAPOFF;
        if ((u & 1) == 0) {
            v2f wv; wv.x = w; wv.y = w;
            #pragma unroll
            for (int k = 0; k < NP; k++) A[k] += wv * wnd[(u >> 1) + k];
        } else {
            #pragma unroll
            for (int k = 0; k < NP; k++) {
                A[k].x += w * wnd[(u >> 1) + k].y;
                A[k].y += w * wnd[(u >> 1) + k + 1].x;
            }
        }
    }
}

// 7-tap strip conv on 4-px strip (2 pairs). Window f[0]=col j0-4, TAPOFF=1.
__device__ __forceinline__ void sconv7(const float* __restrict__ wt, float bb,
                                       const v2f* a, bool pm1, bool np1, v2f* acc) {
    float p1 = dpp<0x111>(a[0].y);   // -> col j0-3
    float p2 = dpp<0x111>(a[1].x);
    float p3 = dpp<0x111>(a[1].y);
    float n0 = dpp<0x101>(a[0].x);   // -> col j0+4
    float n1 = dpp<0x101>(a[0].y);
    float n2 = dpp<0x101>(a[1].x);
    v2f wnd[6];
    wnd[0].x = 0.f;              wnd[0].y = pm1 ? p1 : 0.f;
    wnd[1].x = pm1 ? p2 : 0.f;   wnd[1].y = pm1 ? p3 : 0.f;
    wnd[2] = a[0]; wnd[3] = a[1];
    wnd[4].x = np1 ? n0 : 0.f;   wnd[4].y = np1 ? n1 : 0.f;
    wnd[5].x = np1 ? n2 : 0.f;   wnd[5].y = 0.f;
    acc[0].x = bb; acc[0].y = bb; acc[1].x = bb; acc[1].y = bb;
    conv_acc<7, 1, 2>(wt, wnd, acc);
}

// 11-tap strip conv. Window f[0]=col j0-6, TAPOFF=1 (f[1]=j0-5 .. f[14]=j0+8).
__device__ __forceinline__ void sconv11(const float* __restrict__ wt, float bb,
                                        const v2f* a, bool pm1, bool pm2,
                                        bool np1, bool np2, v2f* acc) {
    float q3 = dpp<0x112>(a[1].y);   // -> col j0-5
    float p0 = dpp<0x111>(a[0].x);   // -> col j0-4
    float p1 = dpp<0x111>(a[0].y);
    float p2 = dpp<0x111>(a[1].x);
    float p3 = dpp<0x111>(a[1].y);
    float n0 = dpp<0x101>(a[0].x);   // -> col j0+4
    float n1 = dpp<0x101>(a[0].y);
    float n2 = dpp<0x101>(a[1].x);
    float n3 = dpp<0x101>(a[1].y);
    float m0 = dpp<0x102>(a[0].x);   // -> col j0+8
    v2f wnd[8];
    wnd[0].x = 0.f;             wnd[0].y = pm2 ? q3 : 0.f;
    wnd[1].x = pm1 ? p0 : 0.f;  wnd[1].y = pm1 ? p1 : 0.f;
    wnd[2].x = pm1 ? p2 : 0.f;  wnd[2].y = pm1 ? p3 : 0.f;
    wnd[3] = a[0]; wnd[4] = a[1];
    wnd[5].x = np1 ? n0 : 0.f;  wnd[5].y = np1 ? n1 : 0.f;
    wnd[6].x = np1 ? n2 : 0.f;  wnd[6].y = np1 ? n3 : 0.f;
    wnd[7].x = np2 ? m0 : 0.f;  wnd[7].y = 0.f;
    acc[0].x = bb; acc[0].y = bb; acc[1].x = bb; acc[1].y = bb;
    conv_acc<11, 1, 2>(wt, wnd, acc);
}

// 21-tap strip conv. Window f[0]=col j0-10, TAPOFF=0 (f[23]=col j0+13).
__device__ __forceinline__ void sconv21(const float* __restrict__ wt, float bb,
                                        const v2f* a, bool pm1, bool pm2, bool pm3,
                                        bool np1, bool np2, bool np3, v2f* acc) {
    float s32 = dpp<0x113>(a[1].x);  // -> col j0-10
    float s33 = dpp<0x113>(a[1].y);  // -> col j0-9
    float s20 = dpp<0x112>(a[0].x);  // -> col j0-8
    float s21 = dpp<0x112>(a[0].y);
    float s22 = dpp<0x112>(a[1].x);
    float s23 = dpp<0x112>(a[1].y);
    float s10 = dpp<0x111>(a[0].x);  // -> col j0-4
    float s11 = dpp<0x111>(a[0].y);
    float s12 = dpp<0x111>(a[1].x);
    float s13 = dpp<0x111>(a[1].y);
    float t10 = dpp<0x101>(a[0].x);  // -> col j0+4
    float t11 = dpp<0x101>(a[0].y);
    float t12 = dpp<0x101>(a[1].x);
    float t13 = dpp<0x101>(a[1].y);
    float t20 = dpp<0x102>(a[0].x);  // -> col j0+8
    float t21 = dpp<0x102>(a[0].y);
    float t22 = dpp<0x102>(a[1].x);
    float t23 = dpp<0x102>(a[1].y);
    float t30 = dpp<0x103>(a[0].x);  // -> col j0+12
    float t31 = dpp<0x103>(a[0].y);  // -> col j0+13
    v2f wnd[12];
    wnd[0].x  = pm3 ? s32 : 0.f;  wnd[0].y  = pm3 ? s33 : 0.f;
    wnd[1].x  = pm2 ? s20 : 0.f;  wnd[1].y  = pm2 ? s21 : 0.f;
    wnd[2].x  = pm2 ? s22 : 0.f;  wnd[2].y  = pm2 ? s23 : 0.f;
    wnd[3].x  = pm1 ? s10 : 0.f;  wnd[3].y  = pm1 ? s11 : 0.f;
    wnd[4].x  = pm1 ? s12 : 0.f;  wnd[4].y  = pm1 ? s13 : 0.f;
    wnd[5] = a[0]; wnd[6] = a[1];
    wnd[7].x  = np1 ? t10 : 0.f;  wnd[7].y  = np1 ? t11 : 0.f;
    wnd[8].x  = np1 ? t12 : 0.f;  wnd[8].y  = np1 ? t13 : 0.f;
    wnd[9].x  = np2 ? t20 : 0.f;  wnd[9].y  = np2 ? t21 : 0.f;
    wnd[10].x = np2 ? t22 : 0.f;  wnd[10].y = np2 ? t23 : 0.f;
    wnd[11].x = np3 ? t30 : 0.f;  wnd[11].y = np3 ? t31 : 0.f;
    acc[0].x = bb; acc[0].y = bb; acc[1].x = bb; acc[1].y = bb;
    conv_acc<21, 0, 2>(wt, wnd, acc);
}

__global__ __launch_bounds__(1024, 8)
void msca_fused(const float* __restrict__ x,
                const float* __restrict__ w0,   const float* __restrict__ b0,
                const float* __restrict__ w0_1, const float* __restrict__ b0_1,
                const float* __restrict__ w0_2, const float* __restrict__ b0_2,
                const float* __restrict__ w1_1, const float* __restrict__ b1_1,
                const float* __restrict__ w1_2, const float* __restrict__ b1_2,
                const float* __restrict__ w2_1, const float* __restrict__ b2_1,
                const float* __restrict__ w2_2, const float* __restrict__ b2_2,
                float* __restrict__ out)
{
    __shared__ __align__(16) float lds[LDS_WORDS];
    float* RT = lds;                // ATT_T
    float* R0 = lds + RW;           // Y0
    float* R1 = lds + 2 * RW;       // Y1
    float* R2 = lds + 3 * RW;       // Y2

    const int t   = threadIdx.x;    // 0..1023
    const int maj = t >> 4;         // X: image row ; T: image col
    const int l16 = t & 15;
    const int j0  = l16 << 2;

    const bool pm1 = l16 >= 1, pm2 = l16 >= 2, pm3 = l16 >= 3;
    const bool np1 = l16 <= 14, np2 = l16 <= 13, np3 = l16 <= 12;

    const int scat = maj ^ (l16 << 2);                            // scatter minor
    const int rdb  = maj * 68 + ((l16 ^ ((maj >> 2) & 15)) << 2); // strip read base

    const int plane = blockIdx.x;
    const int ch    = plane & 255;

    const float* xg = x + (size_t)plane * 4096;
    float* o0 = out + (size_t)plane * 4096;
    float* o1 = o0 + 8388608;
    float* o2 = o1 + 8388608;

    // ---- P1: attn = conv5x5(x)+b0, x direct from global; scatter ATT_T ----
    v2f attn[2];
    {
        const float bb = b0[ch];
        attn[0].x = bb; attn[0].y = bb; attn[1].x = bb; attn[1].y = bb;
        const float* w0p = w0 + ch * 25;
        #pragma unroll
        for (int dr = 0; dr < 5; dr++) {
            const int ri = maj + dr - 2;
            const int rc = ri < 0 ? 0 : (ri > 63 ? 63 : ri);
            const bool valid = (unsigned)ri <= 63u;
            float4 q = *(const float4*)&xg[rc * 64 + j0];
            float a0 = valid ? q.x : 0.f, a1 = valid ? q.y : 0.f;
            float a2 = valid ? q.z : 0.f, a3 = valid ? q.w : 0.f;
            float L0 = dpp<0x111>(a2), L1 = dpp<0x111>(a3);   // cols j0-2,-1
            float Rr0 = dpp<0x101>(a0), Rr1 = dpp<0x101>(a1); // cols j0+4,+5
            v2f wnd[4];                       // f[0]=col j0-2 .. f[7]=j0+5
            wnd[0].x = pm1 ? L0 : 0.f;   wnd[0].y = pm1 ? L1 : 0.f;
            wnd[1].x = a0; wnd[1].y = a1;
            wnd[2].x = a2; wnd[2].y = a3;
            wnd[3].x = np1 ? Rr0 : 0.f;  wnd[3].y = np1 ? Rr1 : 0.f;
            conv_acc<5, 0, 2>(w0p + dr * 5, wnd, attn);
        }
        #pragma unroll
        for (int e = 0; e < 4; e++) RT[(j0 + e) * 68 + scat] = elem(attn, e);
    }
    __syncthreads();   // B1 (ATT_T ready)

    // ---- P2: T-strip read; a0y -> a1y -> a2y packed chain; scatter Y0/Y1/Y2 ----
    {
        v2f stv[2];
        ld4p(&RT[rdb], stv);
        v2f a0y[2];
        sconv7(w0_2 + ch * 7, b0_2[ch], stv, pm1, np1, a0y);
        #pragma unroll
        for (int d = 0; d < 4; d++) R0[(j0 + d) * 68 + scat] = elem(a0y, d);   // Y0
        v2f a1y[2];
        sconv11(w1_2 + ch * 11, b1_2[ch], a0y, pm1, pm2, np1, np2, a1y);
        #pragma unroll
        for (int d = 0; d < 4; d++) R1[(j0 + d) * 68 + scat] = elem(a1y, d);   // Y1
        v2f a2y[2];
        sconv21(w2_2 + ch * 21, b2_2[ch], a1y, pm1, pm2, pm3, np1, np2, np3, a2y);
        #pragma unroll
        for (int d = 0; d < 4; d++) R2[(j0 + d) * 68 + scat] = elem(a2y, d);   // Y2
    }
    __syncthreads();   // B2 (Y0/Y1/Y2 ready)

    // ---- P3: staggered Y reads; x-chain; products; stores ----
    {
        v2f y0r[2];
        ld4p(&R0[rdb], y0r);               // issue; latency under a0x conv
        v2f a0x[2];
        sconv7(w0_1 + ch * 7, b0_1[ch], attn, pm1, np1, a0x);
        st4p(&o0[maj * 64 + j0], a0x[0] * y0r[0], a0x[1] * y0r[1]);

        v2f y1r[2];
        ld4p(&R1[rdb], y1r);               // issue; latency under a1x conv
        v2f a1x[2];
        sconv11(w1_1 + ch * 11, b1_1[ch], a0x, pm1, pm2, np1, np2, a1x);
        st4p(&o1[maj * 64 + j0], a1x[0] * y1r[0], a1x[1] * y1r[1]);

        v2f y2r[2];
        ld4p(&R2[rdb], y2r);               // issue; latency under a2x conv
        v2f a2x[2];
        sconv21(w2_1 + ch * 21, b2_1[ch], a1x, pm1, pm2, pm3, np1, np2, np3, a2x);
        st4p(&o2[maj * 64 + j0], a2x[0] * y2r[0], a2x[1] * y2r[1]);
    }
}

extern "C" void kernel_launch(void* const* d_in, const int* in_sizes, int n_in,
                              void* d_out, int out_size, void* d_ws, size_t ws_size,
                              hipStream_t stream) {
    msca_fused<<<2048, 1024, 0, stream>>>(
        (const float*)d_in[0],
        (const float*)d_in[1],  (const float*)d_in[2],
        (const float*)d_in[3],  (const float*)d_in[4],
        (const float*)d_in[5],  (const float*)d_in[6],
        (const float*)d_in[7],  (const float*)d_in[8],
        (const float*)d_in[9],  (const float*)d_in[10],
        (const float*)d_in[11], (const float*)d_in[12],
        (const float*)d_in[13], (const float*)d_in[14],
        (float*)d_out);
}